// Round 10
// baseline (2205.038 us; speedup 1.0000x reference)
//
#include <hip/hip_runtime.h>

#define N_NODES 100000
#define N_EDGES 3200000
#define IN_CH 24
#define HIDDEN 64
#define N_CLASSES 16

#define NBUCK 782       // ceil(N_NODES / 128), 128-node buckets
#define PHBLOCKS 512
#define PHCHUNK 6250    // phist: 512 * 6250 = E
#define PTBLOCKS 256
#define PTCHUNK 12500   // part: 256 * 12500 = E
#define NSTRIPS (N_NODES / 16)   // 6250 exact

typedef __attribute__((ext_vector_type(8))) short short8;
typedef __attribute__((ext_vector_type(4))) float float4_;
typedef __attribute__((ext_vector_type(2))) float float2v;

__device__ __forceinline__ unsigned short f2bf(float f) {
    union { float f; unsigned int u; } v; v.f = f;
    unsigned int u = v.u;
    return (unsigned short)((u + 0x7FFFu + ((u >> 16) & 1u)) >> 16);
}
// fp8 e4m3 (OCP on gfx950) pack via HW convert
__device__ __forceinline__ unsigned short pk_fp8(float a, float b) {
    return (unsigned short)(__builtin_amdgcn_cvt_pk_fp8_f32(a, b, 0, false) & 0xFFFF);
}

// ---------------- CSR-lite build: coarse bucket partition only ----------------

__global__ __launch_bounds__(1024) void k_phist(const int* __restrict__ dst,
                                                int* __restrict__ bucketCnt) {
    __shared__ int hist[NBUCK];
    int t = threadIdx.x;
    int cbeg = blockIdx.x * PHCHUNK;
    for (int i = t; i < NBUCK; i += 1024) hist[i] = 0;
    __syncthreads();
#pragma unroll
    for (int k = 0; k < 7; k++) {
        int o = k * 1024 + t;
        if (o < PHCHUNK) atomicAdd(&hist[dst[cbeg + o] >> 7], 1);
    }
    __syncthreads();
    for (int i = t; i < NBUCK; i += 1024)
        if (hist[i]) atomicAdd(&bucketCnt[i], hist[i]);
}

__global__ __launch_bounds__(1024) void k_scanb(const int* __restrict__ bucketCnt,
                                                int* __restrict__ bucketBase,
                                                int* __restrict__ bucketFill, int E) {
    __shared__ int lds[1024];
    int t = threadIdx.x;
    int c = (t < NBUCK) ? bucketCnt[t] : 0;
    int val = c;
    lds[t] = val;
    __syncthreads();
    for (int off = 1; off < 1024; off <<= 1) {
        int v = (t >= off) ? lds[t - off] : 0;
        __syncthreads();
        val += v;
        lds[t] = val;
        __syncthreads();
    }
    if (t < NBUCK) {
        int ex = val - c;
        bucketBase[t] = ex;
        bucketFill[t] = ex;
    }
    if (t == 0) bucketBase[NBUCK] = E;
}

// register-stash partition: src/dst read ONCE; 12.5K-edge chunks halve
// per-(block,bucket) segment boundary RMW vs 6.25K chunks
__global__ __launch_bounds__(1024) void k_part(const int* __restrict__ src,
                                               const int* __restrict__ dst,
                                               int* __restrict__ bucketFill,
                                               unsigned int* __restrict__ pedges) {
    __shared__ int cntL[NBUCK];
    __shared__ int baseL[NBUCK];
    int t = threadIdx.x;
    int cbeg = blockIdx.x * PTCHUNK;
    int d[13], s[13];
#pragma unroll
    for (int k = 0; k < 13; k++) {
        int o = k * 1024 + t;
        bool ok = o < PTCHUNK;
        d[k] = ok ? dst[cbeg + o] : -1;
        s[k] = ok ? src[cbeg + o] : 0;
    }
    for (int i = t; i < NBUCK; i += 1024) cntL[i] = 0;
    __syncthreads();
#pragma unroll
    for (int k = 0; k < 13; k++)
        if (d[k] >= 0) atomicAdd(&cntL[d[k] >> 7], 1);
    __syncthreads();
    for (int i = t; i < NBUCK; i += 1024) {
        int c = cntL[i];
        if (c) baseL[i] = atomicAdd(&bucketFill[i], c);
        cntL[i] = 0;
    }
    __syncthreads();
#pragma unroll
    for (int k = 0; k < 13; k++)
        if (d[k] >= 0) {
            int bk = d[k] >> 7;
            int r = atomicAdd(&cntL[bk], 1);
            pedges[baseL[bk] + r] = ((unsigned int)(d[k] & 127) << 17) | (unsigned int)s[k];
        }
}

// ---------------- weight prep ----------------

__global__ __launch_bounds__(256) void k_prep(const float* __restrict__ W1l,
                                              const float* __restrict__ W1r,
                                              const float* __restrict__ W2l,
                                              const float* __restrict__ W2r,
                                              const float* __restrict__ Wc,
                                              const float* __restrict__ b2,
                                              const float* __restrict__ bc,
                                              unsigned short* __restrict__ Bt1,
                                              unsigned short* __restrict__ Bt2,
                                              float* __restrict__ bias2) {
    int t = threadIdx.x;
    for (int i = t; i < 64 * 64; i += 256) {
        int o = i >> 6, k = i & 63;
        float v = (k < 24) ? W1r[o * 24 + k] : ((k < 48) ? W1l[o * 24 + k - 24] : 0.f);
        Bt1[i] = f2bf(v);
    }
    for (int i = t; i < 64 * 128; i += 256) {
        int o = i >> 7, k = i & 127;
        float v = (k < 64) ? W2l[o * 64 + k] : W2r[o * 64 + k - 64];
        Bt2[i] = f2bf(v);
    }
    for (int i = t; i < 16 * 128; i += 256) {
        int c = i >> 7, k = i & 127;
        const float* M = (k < 64) ? W2l : W2r;
        int kk = k & 63;
        float s = 0.f;
        for (int j = 0; j < 64; j++) s += Wc[c * 64 + j] * M[j * 64 + kk];
        Bt2[(64 + c) * 128 + k] = f2bf(s);
    }
    for (int i = t; i < 80; i += 256) {
        if (i < 64) bias2[i] = b2[i];
        else {
            int c = i - 64;
            float s = bc[c];
            for (int j = 0; j < 64; j++) s += Wc[c * 64 + j] * b2[j];
            bias2[i] = s;
        }
    }
}

// x fp32 -> A1 bf16 x-zone + X8 fp8 rows. A1 pad (dwords 24..31) stays as
// 0xAA poison: finite bf16 (-2.6e-13) x exact-zero Bt1 columns = 0. X8 pad
// bytes feed ignored LDS columns in agg1.
__global__ __launch_bounds__(256) void k_castx(const float* __restrict__ x,
                                               unsigned int* __restrict__ A1u,
                                               unsigned short* __restrict__ X8s) {
    int gid = blockIdx.x * 256 + threadIdx.x;
    if (gid >= N_NODES * 16) return;
    int n = gid >> 4, kp = gid & 15;
    if (kp >= 12) return;
    const float2 v = *(const float2*)(x + n * 24 + kp * 2);
    A1u[n * 32 + kp] = (unsigned int)f2bf(v.x) | ((unsigned int)f2bf(v.y) << 16);
    X8s[n * 16 + kp] = pk_fp8(v.x, v.y);
}

// ---------------- aggregations: bucket-parallel, LDS fp32 accumulate --------

// agg1: block = one 128-node bucket; 4 lanes/edge gather 8B of 32B X8 row;
// ds_add_f32 into LDS acc (stride 33; cols 24..31 absorb pad garbage).
__global__ __launch_bounds__(512) void k_agg1(const unsigned int* __restrict__ X8u,
                                              const unsigned int* __restrict__ pedges,
                                              const int* __restrict__ bucketBase,
                                              unsigned int* __restrict__ A1w, int N) {
    __shared__ float acc[128 * 33];
    __shared__ int degL[128];
    int b = blockIdx.x, t = threadIdx.x;
    int eb = bucketBase[b], m = bucketBase[b + 1] - eb;
    for (int i = t; i < 128 * 33; i += 512) acc[i] = 0.f;
    if (t < 128) degL[t] = 0;
    __syncthreads();
    int grp = t >> 2, sub = t & 3;     // 128 edge slots x 4 lanes
    const unsigned int* basep = X8u + sub * 2;
    for (int j = 0; j < m; j += 512) {
        int e0 = j + grp, e1 = e0 + 128, e2 = e0 + 256, e3 = e0 + 384;
        unsigned int p0 = (e0 < m) ? pedges[eb + e0] : 0xFFFFFFFFu;
        unsigned int p1 = (e1 < m) ? pedges[eb + e1] : 0xFFFFFFFFu;
        unsigned int p2 = (e2 < m) ? pedges[eb + e2] : 0xFFFFFFFFu;
        unsigned int p3 = (e3 < m) ? pedges[eb + e3] : 0xFFFFFFFFu;
        unsigned int s0 = (p0 != 0xFFFFFFFFu) ? (p0 & 0x1FFFFu) : 0u;
        unsigned int s1 = (p1 != 0xFFFFFFFFu) ? (p1 & 0x1FFFFu) : 0u;
        unsigned int s2 = (p2 != 0xFFFFFFFFu) ? (p2 & 0x1FFFFu) : 0u;
        unsigned int s3 = (p3 != 0xFFFFFFFFu) ? (p3 & 0x1FFFFu) : 0u;
        uint2 u0 = *(const uint2*)(basep + (size_t)s0 * 8);
        uint2 u1 = *(const uint2*)(basep + (size_t)s1 * 8);
        uint2 u2 = *(const uint2*)(basep + (size_t)s2 * 8);
        uint2 u3 = *(const uint2*)(basep + (size_t)s3 * 8);
        unsigned int pp[4] = {p0, p1, p2, p3};
        uint2 uu[4] = {u0, u1, u2, u3};
#pragma unroll
        for (int k = 0; k < 4; k++) {
            if (pp[k] != 0xFFFFFFFFu) {
                int d = (int)(pp[k] >> 17);
                float* row = acc + d * 33 + sub * 8;
                float2v f0 = __builtin_amdgcn_cvt_pk_f32_fp8(uu[k].x, false);
                float2v f1 = __builtin_amdgcn_cvt_pk_f32_fp8(uu[k].x, true);
                float2v f2 = __builtin_amdgcn_cvt_pk_f32_fp8(uu[k].y, false);
                float2v f3 = __builtin_amdgcn_cvt_pk_f32_fp8(uu[k].y, true);
                atomicAdd(row + 0, f0.x); atomicAdd(row + 1, f0.y);
                atomicAdd(row + 2, f1.x); atomicAdd(row + 3, f1.y);
                atomicAdd(row + 4, f2.x); atomicAdd(row + 5, f2.y);
                atomicAdd(row + 6, f3.x); atomicAdd(row + 7, f3.y);
                if (sub == 0) atomicAdd(&degL[d], 1);
            }
        }
    }
    __syncthreads();
    int n = t >> 2, q = t & 3;   // node-local, quarter (6 channels = 3 dwords)
    int node = b * 128 + n;
    if (node < N) {
        float inv = 1.f / (float)max(degL[n], 1);
        const float* row = acc + n * 33 + q * 6;
        unsigned int* outp = A1w + (size_t)node * 32 + 12 + q * 3;
#pragma unroll
        for (int c = 0; c < 3; c++)
            outp[c] = (unsigned int)f2bf(row[2 * c] * inv) |
                      ((unsigned int)f2bf(row[2 * c + 1] * inv) << 16);
    }
}

// agg2: block = one 128-node bucket; 8 lanes/edge gather 8B of 64B H8 row;
// ds_add_f32 into LDS acc (stride 66).
__global__ __launch_bounds__(512) void k_agg2(const unsigned int* __restrict__ H8u,
                                              const unsigned int* __restrict__ pedges,
                                              const int* __restrict__ bucketBase,
                                              unsigned int* __restrict__ A2w, int N) {
    __shared__ float acc[128 * 66];
    __shared__ int degL[128];
    int b = blockIdx.x, t = threadIdx.x;
    int eb = bucketBase[b], m = bucketBase[b + 1] - eb;
    for (int i = t; i < 128 * 66; i += 512) acc[i] = 0.f;
    if (t < 128) degL[t] = 0;
    __syncthreads();
    int grp = t >> 3, sub = t & 7;     // 64 edge slots x 8 lanes
    const unsigned int* basep = H8u + sub * 2;
    for (int j = 0; j < m; j += 256) {
        int e0 = j + grp, e1 = e0 + 64, e2 = e0 + 128, e3 = e0 + 192;
        unsigned int p0 = (e0 < m) ? pedges[eb + e0] : 0xFFFFFFFFu;
        unsigned int p1 = (e1 < m) ? pedges[eb + e1] : 0xFFFFFFFFu;
        unsigned int p2 = (e2 < m) ? pedges[eb + e2] : 0xFFFFFFFFu;
        unsigned int p3 = (e3 < m) ? pedges[eb + e3] : 0xFFFFFFFFu;
        unsigned int s0 = (p0 != 0xFFFFFFFFu) ? (p0 & 0x1FFFFu) : 0u;
        unsigned int s1 = (p1 != 0xFFFFFFFFu) ? (p1 & 0x1FFFFu) : 0u;
        unsigned int s2 = (p2 != 0xFFFFFFFFu) ? (p2 & 0x1FFFFu) : 0u;
        unsigned int s3 = (p3 != 0xFFFFFFFFu) ? (p3 & 0x1FFFFu) : 0u;
        uint2 u0 = *(const uint2*)(basep + (size_t)s0 * 16);
        uint2 u1 = *(const uint2*)(basep + (size_t)s1 * 16);
        uint2 u2 = *(const uint2*)(basep + (size_t)s2 * 16);
        uint2 u3 = *(const uint2*)(basep + (size_t)s3 * 16);
        unsigned int pp[4] = {p0, p1, p2, p3};
        uint2 uu[4] = {u0, u1, u2, u3};
#pragma unroll
        for (int k = 0; k < 4; k++) {
            if (pp[k] != 0xFFFFFFFFu) {
                int d = (int)(pp[k] >> 17);
                float* row = acc + d * 66 + sub * 8;
                float2v f0 = __builtin_amdgcn_cvt_pk_f32_fp8(uu[k].x, false);
                float2v f1 = __builtin_amdgcn_cvt_pk_f32_fp8(uu[k].x, true);
                float2v f2 = __builtin_amdgcn_cvt_pk_f32_fp8(uu[k].y, false);
                float2v f3 = __builtin_amdgcn_cvt_pk_f32_fp8(uu[k].y, true);
                atomicAdd(row + 0, f0.x); atomicAdd(row + 1, f0.y);
                atomicAdd(row + 2, f1.x); atomicAdd(row + 3, f1.y);
                atomicAdd(row + 4, f2.x); atomicAdd(row + 5, f2.y);
                atomicAdd(row + 6, f3.x); atomicAdd(row + 7, f3.y);
                if (sub == 0) atomicAdd(&degL[d], 1);
            }
        }
    }
    __syncthreads();
    int n = t >> 2, q = t & 3;   // node-local, quarter (16 channels = 8 dwords)
    int node = b * 128 + n;
    if (node < N) {
        float inv = 1.f / (float)max(degL[n], 1);
        const float* row = acc + n * 66 + q * 16;
        unsigned int* outp = A2w + (size_t)node * 64 + q * 8;
#pragma unroll
        for (int c = 0; c < 8; c++)
            outp[c] = (unsigned int)f2bf(row[2 * c] * inv) |
                      ((unsigned int)f2bf(row[2 * c + 1] * inv) << 16);
    }
}

// ---------------- MFMA GEMMs (no LDS; B^T in registers) ----------------

// h = relu(A1 @ Bt1^T + b1): bf16 into A2 h-half AND fp8 into H8
__global__ __launch_bounds__(256) void k_gemm1(const unsigned short* __restrict__ A1,
                                               const unsigned short* __restrict__ Bt1,
                                               const float* __restrict__ b1,
                                               unsigned short* __restrict__ A2s,
                                               unsigned char* __restrict__ H8b) {
    int wave = (blockIdx.x * 256 + threadIdx.x) >> 6;
    int lane = threadIdx.x & 63;
    int m = lane & 15, quad = lane >> 4;
    if (wave >= NSTRIPS) return;
    short8 bf[4][2];
#pragma unroll
    for (int t = 0; t < 4; t++)
#pragma unroll
        for (int s = 0; s < 2; s++)
            bf[t][s] = *(const short8*)(Bt1 + (t * 16 + m) * 64 + s * 32 + quad * 8);
    float bias[4];
#pragma unroll
    for (int t = 0; t < 4; t++) bias[t] = b1[t * 16 + m];

    int row0 = wave * 16;
    short8 a0 = *(const short8*)(A1 + (row0 + m) * 64 + quad * 8);
    short8 a1 = *(const short8*)(A1 + (row0 + m) * 64 + 32 + quad * 8);
    float4_ acc[4];
#pragma unroll
    for (int t = 0; t < 4; t++) {
        float4_ c = {0.f, 0.f, 0.f, 0.f};
        c = __builtin_amdgcn_mfma_f32_16x16x32_bf16(a0, bf[t][0], c, 0, 0, 0);
        c = __builtin_amdgcn_mfma_f32_16x16x32_bf16(a1, bf[t][1], c, 0, 0, 0);
        acc[t] = c;
    }
#pragma unroll
    for (int t = 0; t < 4; t++) {
        int col = t * 16 + m;
#pragma unroll
        for (int r = 0; r < 4; r++) {
            int row = row0 + quad * 4 + r;
            float v = fmaxf(acc[t][r] + bias[t], 0.f);
            A2s[row * 128 + 64 + col] = f2bf(v);
            H8b[row * 64 + col] =
                (unsigned char)(__builtin_amdgcn_cvt_pk_fp8_f32(v, 0.f, 0, false) & 0xFF);
        }
    }
}

__global__ __launch_bounds__(256) void k_gemm2(const unsigned short* __restrict__ Bt2,
                                               const float* __restrict__ bias2,
                                               unsigned short* A2s,
                                               float* logits) {
    int wave = (blockIdx.x * 256 + threadIdx.x) >> 6;
    int lane = threadIdx.x & 63;
    int m = lane & 15, quad = lane >> 4;
    if (wave >= NSTRIPS) return;
    short8 bf[5][4];
#pragma unroll
    for (int t = 0; t < 5; t++)
#pragma unroll
        for (int s = 0; s < 4; s++)
            bf[t][s] = *(const short8*)(Bt2 + (t * 16 + m) * 128 + s * 32 + quad * 8);
    float bias[5];
#pragma unroll
    for (int t = 0; t < 5; t++) bias[t] = bias2[t * 16 + m];

    int row0 = wave * 16;
    short8 a[4];
#pragma unroll
    for (int s = 0; s < 4; s++)
        a[s] = *(const short8*)(A2s + (row0 + m) * 128 + s * 32 + quad * 8);
    float4_ acc[5];
#pragma unroll
    for (int t = 0; t < 5; t++) {
        float4_ c = {0.f, 0.f, 0.f, 0.f};
#pragma unroll
        for (int s = 0; s < 4; s++)
            c = __builtin_amdgcn_mfma_f32_16x16x32_bf16(a[s], bf[t][s], c, 0, 0, 0);
        acc[t] = c;
    }
    float* embp = (float*)A2s;
#pragma unroll
    for (int t = 0; t < 4; t++) {
#pragma unroll
        for (int r = 0; r < 4; r++) {
            int row = row0 + quad * 4 + r;
            embp[row * 64 + t * 16 + m] = acc[t][r] + bias[t];
        }
    }
#pragma unroll
    for (int r = 0; r < 4; r++) {
        int row = row0 + quad * 4 + r;
        logits[row * 16 + m] = acc[4][r] + bias[4];
    }
}

// ---------------- launch ----------------

extern "C" void kernel_launch(void* const* d_in, const int* in_sizes, int n_in,
                              void* d_out, int out_size, void* d_ws, size_t ws_size,
                              hipStream_t stream) {
    const float* x = (const float*)d_in[0];
    const int* edge = (const int*)d_in[1];
    const int* srcIdx = edge;
    const int* dstIdx = edge + N_EDGES;
    const float* W1l = (const float*)d_in[2];
    const float* b1  = (const float*)d_in[3];
    const float* W1r = (const float*)d_in[4];
    const float* W2l = (const float*)d_in[5];
    const float* b2  = (const float*)d_in[6];
    const float* W2r = (const float*)d_in[7];
    const float* Wc  = (const float*)d_in[8];
    const float* bc  = (const float*)d_in[9];

    float* logits = (float*)d_out;
    unsigned short* A2s = (unsigned short*)((float*)d_out + (size_t)N_NODES * N_CLASSES);
    unsigned int* A2u = (unsigned int*)A2s;

    char* w = (char*)d_ws;
    auto carve = [&](size_t bytes) {
        char* p = w;
        w += (bytes + 255) & ~(size_t)255;
        return p;
    };
    unsigned int* pedges = (unsigned int*)carve((size_t)N_EDGES * sizeof(unsigned int));
    unsigned int* A1u    = (unsigned int*)carve((size_t)N_NODES * 32 * sizeof(unsigned int));
    unsigned short* X8s  = (unsigned short*)carve((size_t)N_NODES * 32);   // fp8 x, 32B rows
    unsigned char* H8b   = (unsigned char*)carve((size_t)N_NODES * 64);    // fp8 h, 64B rows
    int* bucketCnt       = (int*)carve(NBUCK * sizeof(int));
    int* bucketBase      = (int*)carve((NBUCK + 1) * sizeof(int));
    int* bucketFill      = (int*)carve(NBUCK * sizeof(int));
    unsigned short* Bt1  = (unsigned short*)carve(64 * 64 * sizeof(unsigned short));
    unsigned short* Bt2  = (unsigned short*)carve(80 * 128 * sizeof(unsigned short));
    float* bias2         = (float*)carve(80 * sizeof(float));

    unsigned short* A1s = (unsigned short*)A1u;
    unsigned int* X8u = (unsigned int*)X8s;
    unsigned int* H8u = (unsigned int*)H8b;

    k_prep<<<1, 256, 0, stream>>>(W1l, W1r, W2l, W2r, Wc, b2, bc, Bt1, Bt2, bias2);

    hipMemsetAsync(bucketCnt, 0, NBUCK * sizeof(int), stream);
    k_phist<<<PHBLOCKS, 1024, 0, stream>>>(dstIdx, bucketCnt);
    k_scanb<<<1, 1024, 0, stream>>>(bucketCnt, bucketBase, bucketFill, N_EDGES);
    k_part<<<PTBLOCKS, 1024, 0, stream>>>(srcIdx, dstIdx, bucketFill, pedges);

    k_castx<<<(N_NODES * 16 + 255) / 256, 256, 0, stream>>>(x, A1u, X8s);
    k_agg1<<<NBUCK, 512, 0, stream>>>(X8u, pedges, bucketBase, A1u, N_NODES);
    k_gemm1<<<(NSTRIPS + 3) / 4, 256, 0, stream>>>(A1s, Bt1, b1, A2s, H8b);
    k_agg2<<<NBUCK, 512, 0, stream>>>(H8u, pedges, bucketBase, A2u, N_NODES);
    k_gemm2<<<(NSTRIPS + 3) / 4, 256, 0, stream>>>(Bt2, bias2, A2s, logits);
}

// Round 11
// 308.919 us; speedup vs baseline: 7.1379x; 7.1379x over previous
//
#include <hip/hip_runtime.h>

#define N_NODES 100000
#define N_EDGES 3200000
#define IN_CH 24
#define HIDDEN 64
#define N_CLASSES 16

#define NBUCK 782       // ceil(N_NODES / 128), 128-node buckets
#define PHBLOCKS 512
#define PHCHUNK 6250    // phist: 512 * 6250 = E
#define PTBLOCKS 256
#define PTCHUNK 12500   // part: 256 * 12500 = E
#define NSTRIPS (N_NODES / 16)   // 6250 exact

typedef __attribute__((ext_vector_type(8))) short short8;
typedef __attribute__((ext_vector_type(4))) float float4_;
typedef __attribute__((ext_vector_type(2))) float float2v;

__device__ __forceinline__ unsigned short f2bf(float f) {
    union { float f; unsigned int u; } v; v.f = f;
    unsigned int u = v.u;
    return (unsigned short)((u + 0x7FFFu + ((u >> 16) & 1u)) >> 16);
}
// fp8 e4m3 (OCP on gfx950) pack/unpack via HW converts
__device__ __forceinline__ unsigned short pk_fp8(float a, float b) {
    return (unsigned short)(__builtin_amdgcn_cvt_pk_fp8_f32(a, b, 0, false) & 0xFFFF);
}
__device__ __forceinline__ void accum8(float2v* A, uint2 u) {
    A[0] += __builtin_amdgcn_cvt_pk_f32_fp8(u.x, false);
    A[1] += __builtin_amdgcn_cvt_pk_f32_fp8(u.x, true);
    A[2] += __builtin_amdgcn_cvt_pk_f32_fp8(u.y, false);
    A[3] += __builtin_amdgcn_cvt_pk_f32_fp8(u.y, true);
}

// ---------------- CSR build (two-level partition) ----------------

__global__ __launch_bounds__(1024) void k_phist(const int* __restrict__ dst,
                                                int* __restrict__ bucketCnt) {
    __shared__ int hist[NBUCK];
    int t = threadIdx.x;
    int cbeg = blockIdx.x * PHCHUNK;
    for (int i = t; i < NBUCK; i += 1024) hist[i] = 0;
    __syncthreads();
#pragma unroll
    for (int k = 0; k < 7; k++) {
        int o = k * 1024 + t;
        if (o < PHCHUNK) atomicAdd(&hist[dst[cbeg + o] >> 7], 1);
    }
    __syncthreads();
    for (int i = t; i < NBUCK; i += 1024)
        if (hist[i]) atomicAdd(&bucketCnt[i], hist[i]);
}

__global__ __launch_bounds__(1024) void k_scanb(const int* __restrict__ bucketCnt,
                                                int* __restrict__ bucketBase,
                                                int* __restrict__ bucketFill,
                                                int* __restrict__ srcs, int E) {
    __shared__ int lds[1024];
    int t = threadIdx.x;
    int c = (t < NBUCK) ? bucketCnt[t] : 0;
    int val = c;
    lds[t] = val;
    __syncthreads();
    for (int off = 1; off < 1024; off <<= 1) {
        int v = (t >= off) ? lds[t - off] : 0;
        __syncthreads();
        val += v;
        lds[t] = val;
        __syncthreads();
    }
    if (t < NBUCK) {
        int ex = val - c;
        bucketBase[t] = ex;
        bucketFill[t] = ex;
    }
    if (t == 0) bucketBase[NBUCK] = E;
    if (t < 32) srcs[E + t] = 0;   // zero tail for masked gathers
}

// register-stash partition: src/dst read ONCE; 12.5K-edge chunks halve
// per-(block,bucket) segment-boundary RMW vs 6.25K chunks
__global__ __launch_bounds__(1024) void k_part(const int* __restrict__ src,
                                               const int* __restrict__ dst,
                                               int* __restrict__ bucketFill,
                                               unsigned int* __restrict__ pedges) {
    __shared__ int cntL[NBUCK];
    __shared__ int baseL[NBUCK];
    int t = threadIdx.x;
    int cbeg = blockIdx.x * PTCHUNK;
    int d[13], s[13];
#pragma unroll
    for (int k = 0; k < 13; k++) {
        int o = k * 1024 + t;
        bool ok = o < PTCHUNK;
        d[k] = ok ? dst[cbeg + o] : -1;
        s[k] = ok ? src[cbeg + o] : 0;
    }
    for (int i = t; i < NBUCK; i += 1024) cntL[i] = 0;
    __syncthreads();
#pragma unroll
    for (int k = 0; k < 13; k++)
        if (d[k] >= 0) atomicAdd(&cntL[d[k] >> 7], 1);
    __syncthreads();
    for (int i = t; i < NBUCK; i += 1024) {
        int c = cntL[i];
        if (c) baseL[i] = atomicAdd(&bucketFill[i], c);
        cntL[i] = 0;
    }
    __syncthreads();
#pragma unroll
    for (int k = 0; k < 13; k++)
        if (d[k] >= 0) {
            int bk = d[k] >> 7;
            int r = atomicAdd(&cntL[bk], 1);
            pedges[baseL[bk] + r] = ((unsigned int)(d[k] & 127) << 17) | (unsigned int)s[k];
        }
}

// per-bucket finalize, 128-node buckets, register-stashed pedges (int atomics
// in LDS are fine — it's FLOAT LDS atomics that are catastrophic [R9])
__global__ __launch_bounds__(1024) void k_bucket(const unsigned int* __restrict__ pedges,
                                                 const int* __restrict__ bucketBase,
                                                 int* __restrict__ rowptr,
                                                 int* __restrict__ srcs, int N, int E) {
    __shared__ int ncnt[128];
    __shared__ int sps[128];
    int b = blockIdx.x;
    int t = threadIdx.x;
    int eb = bucketBase[b], ee = bucketBase[b + 1];
    int m = ee - eb;
    unsigned int v[8];
#pragma unroll
    for (int k = 0; k < 8; k++) {
        int o = k * 1024 + t;
        v[k] = (o < m) ? pedges[eb + o] : 0xFFFFFFFFu;
    }
    if (t < 128) ncnt[t] = 0;
    __syncthreads();
#pragma unroll
    for (int k = 0; k < 8; k++)
        if (v[k] != 0xFFFFFFFFu) atomicAdd(&ncnt[v[k] >> 17], 1);
    __syncthreads();
    int myc = (t < 128) ? ncnt[t] : 0;
    int val = myc;
    if (t < 128) sps[t] = val;
    __syncthreads();
    for (int off = 1; off < 128; off <<= 1) {
        int vv = (t >= off && t < 128) ? sps[t - off] : 0;
        __syncthreads();
        if (t < 128) { val += vv; sps[t] = val; }
        __syncthreads();
    }
    int mybase = val - myc;
    int node = b * 128 + t;
    if (t < 128 && node < N) rowptr[node] = eb + mybase;
    if (b == 0 && t == 0) rowptr[N] = E;
    if (t < 128) { sps[t] = mybase; ncnt[t] = 0; }
    __syncthreads();
#pragma unroll
    for (int k = 0; k < 8; k++)
        if (v[k] != 0xFFFFFFFFu) {
            unsigned int nl = v[k] >> 17;
            int r = atomicAdd(&ncnt[nl], 1);
            srcs[eb + sps[nl] + r] = (int)(v[k] & 0x1FFFF);
        }
}

// ---------------- weight prep ----------------

__global__ __launch_bounds__(256) void k_prep(const float* __restrict__ W1l,
                                              const float* __restrict__ W1r,
                                              const float* __restrict__ W2l,
                                              const float* __restrict__ W2r,
                                              const float* __restrict__ Wc,
                                              const float* __restrict__ b2,
                                              const float* __restrict__ bc,
                                              unsigned short* __restrict__ Bt1,
                                              unsigned short* __restrict__ Bt2,
                                              float* __restrict__ bias2) {
    int t = threadIdx.x;
    for (int i = t; i < 64 * 64; i += 256) {
        int o = i >> 6, k = i & 63;
        float v = (k < 24) ? W1r[o * 24 + k] : ((k < 48) ? W1l[o * 24 + k - 24] : 0.f);
        Bt1[i] = f2bf(v);
    }
    for (int i = t; i < 64 * 128; i += 256) {
        int o = i >> 7, k = i & 127;
        float v = (k < 64) ? W2l[o * 64 + k] : W2r[o * 64 + k - 64];
        Bt2[i] = f2bf(v);
    }
    for (int i = t; i < 16 * 128; i += 256) {
        int c = i >> 7, k = i & 127;
        const float* M = (k < 64) ? W2l : W2r;
        int kk = k & 63;
        float s = 0.f;
        for (int j = 0; j < 64; j++) s += Wc[c * 64 + j] * M[j * 64 + kk];
        Bt2[(64 + c) * 128 + k] = f2bf(s);
    }
    for (int i = t; i < 80; i += 256) {
        if (i < 64) bias2[i] = b2[i];
        else {
            int c = i - 64;
            float s = bc[c];
            for (int j = 0; j < 64; j++) s += Wc[c * 64 + j] * b2[j];
            bias2[i] = s;
        }
    }
}

// x fp32 -> A1 bf16 x-zone + zeroed pad (pedges aliases A1u — Inf/NaN hazard)
//        -> X8 fp8 rows (32 B: 24 real + 8 zero pad)
__global__ __launch_bounds__(256) void k_castx(const float* __restrict__ x,
                                               unsigned int* __restrict__ A1u,
                                               unsigned short* __restrict__ X8s) {
    int gid = blockIdx.x * 256 + threadIdx.x;
    if (gid >= N_NODES * 16) return;
    int n = gid >> 4, kp = gid & 15;
    if (kp < 12) {
        const float2 v = *(const float2*)(x + n * 24 + kp * 2);
        A1u[n * 32 + kp] = (unsigned int)f2bf(v.x) | ((unsigned int)f2bf(v.y) << 16);
        X8s[n * 16 + kp] = pk_fp8(v.x, v.y);
    } else {
        int p = kp - 12;
        uint2 z; z.x = 0u; z.y = 0u;
        *(uint2*)(A1u + n * 32 + 24 + p * 2) = z;
        X8s[n * 16 + kp] = 0;
    }
}

// ---------------- aggregations (fp8 gather tables) ----------------

// agg1: gather 32B X8 rows, 4 lanes/edge (uint2 = 8 fp8), 32 edges/iter
__global__ __launch_bounds__(256) void k_agg1(const unsigned int* __restrict__ X8u,
                                              const int* __restrict__ rowptr,
                                              const int* __restrict__ srcs,
                                              unsigned int* __restrict__ A1w, int N) {
    int node = (blockIdx.x * 256 + threadIdx.x) >> 6;
    int lane = threadIdx.x & 63;
    if (node >= N) return;
    int b = rowptr[node], e = rowptr[node + 1];
    int grp = lane >> 2;    // 0..15 edge slot
    int sub = lane & 3;     // 8B chunk of 32B row (channels sub*8..+7)
    const unsigned int* basep = X8u + sub * 2;
    float2v A[4] = {{0.f, 0.f}, {0.f, 0.f}, {0.f, 0.f}, {0.f, 0.f}};
    int nfull = (e - b) & ~31;
    int j = b;
    for (; j < b + nfull; j += 32) {
        int s0 = srcs[j + grp];
        int s1 = srcs[j + 16 + grp];
        uint2 u0 = *(const uint2*)(basep + (size_t)s0 * 8);
        uint2 u1 = *(const uint2*)(basep + (size_t)s1 * 8);
        accum8(A, u0);
        accum8(A, u1);
    }
    if (j < e) {
        int j0 = j + grp, j1 = j0 + 16;
        int s0 = srcs[j0], s1 = srcs[j1];
        uint2 u0 = *(const uint2*)(basep + (size_t)s0 * 8);
        uint2 u1 = *(const uint2*)(basep + (size_t)s1 * 8);
        if (j0 >= e) { u0.x = 0; u0.y = 0; }
        if (j1 >= e) { u1.x = 0; u1.y = 0; }
        accum8(A, u0);
        accum8(A, u1);
    }
#pragma unroll
    for (int m = 4; m <= 32; m <<= 1) {
#pragma unroll
        for (int q = 0; q < 4; q++) {
            A[q].x += __shfl_xor(A[q].x, m, 64);
            A[q].y += __shfl_xor(A[q].y, m, 64);
        }
    }
    if (lane < 4) {
        // sub==3 holds sums of X8 pad bytes (zeros) -> writes zeros to pad dwords 24..27
        float inv = 1.f / (float)max(e - b, 1);
        uint4 o;
        o.x = (unsigned int)f2bf(A[0].x * inv) | ((unsigned int)f2bf(A[0].y * inv) << 16);
        o.y = (unsigned int)f2bf(A[1].x * inv) | ((unsigned int)f2bf(A[1].y * inv) << 16);
        o.z = (unsigned int)f2bf(A[2].x * inv) | ((unsigned int)f2bf(A[2].y * inv) << 16);
        o.w = (unsigned int)f2bf(A[3].x * inv) | ((unsigned int)f2bf(A[3].y * inv) << 16);
        *(uint4*)(A1w + (size_t)node * 32 + 12 + sub * 4) = o;
    }
}

// agg2: gather 64B H8 rows, 8 lanes/edge (uint2 = 8 fp8), 32 edges/iter
__global__ __launch_bounds__(256) void k_agg2(const unsigned int* __restrict__ H8u,
                                              const int* __restrict__ rowptr,
                                              const int* __restrict__ srcs,
                                              unsigned int* __restrict__ A2w, int N) {
    int node = (blockIdx.x * 256 + threadIdx.x) >> 6;
    int lane = threadIdx.x & 63;
    if (node >= N) return;
    int b = rowptr[node], e = rowptr[node + 1];
    int grp = lane >> 3;    // 0..7 edge slot
    int sub = lane & 7;     // 8B chunk of 64B row (channels sub*8..+7)
    const unsigned int* basep = H8u + sub * 2;
    float2v A[4] = {{0.f, 0.f}, {0.f, 0.f}, {0.f, 0.f}, {0.f, 0.f}};
    int nfull = (e - b) & ~31;
    int j = b;
    for (; j < b + nfull; j += 32) {
        int s0 = srcs[j + grp];
        int s1 = srcs[j + 8 + grp];
        int s2 = srcs[j + 16 + grp];
        int s3 = srcs[j + 24 + grp];
        uint2 u0 = *(const uint2*)(basep + (size_t)s0 * 16);
        uint2 u1 = *(const uint2*)(basep + (size_t)s1 * 16);
        uint2 u2 = *(const uint2*)(basep + (size_t)s2 * 16);
        uint2 u3 = *(const uint2*)(basep + (size_t)s3 * 16);
        accum8(A, u0);
        accum8(A, u1);
        accum8(A, u2);
        accum8(A, u3);
    }
    if (j < e) {
        int j0 = j + grp, j1 = j0 + 8, j2 = j0 + 16, j3 = j0 + 24;
        int s0 = srcs[j0], s1 = srcs[j1], s2 = srcs[j2], s3 = srcs[j3];
        uint2 u0 = *(const uint2*)(basep + (size_t)s0 * 16);
        uint2 u1 = *(const uint2*)(basep + (size_t)s1 * 16);
        uint2 u2 = *(const uint2*)(basep + (size_t)s2 * 16);
        uint2 u3 = *(const uint2*)(basep + (size_t)s3 * 16);
        if (j0 >= e) { u0.x = 0; u0.y = 0; }
        if (j1 >= e) { u1.x = 0; u1.y = 0; }
        if (j2 >= e) { u2.x = 0; u2.y = 0; }
        if (j3 >= e) { u3.x = 0; u3.y = 0; }
        accum8(A, u0);
        accum8(A, u1);
        accum8(A, u2);
        accum8(A, u3);
    }
#pragma unroll
    for (int m = 8; m <= 32; m <<= 1) {
#pragma unroll
        for (int q = 0; q < 4; q++) {
            A[q].x += __shfl_xor(A[q].x, m, 64);
            A[q].y += __shfl_xor(A[q].y, m, 64);
        }
    }
    if (lane < 8) {
        float inv = 1.f / (float)max(e - b, 1);
        uint4 o;
        o.x = (unsigned int)f2bf(A[0].x * inv) | ((unsigned int)f2bf(A[0].y * inv) << 16);
        o.y = (unsigned int)f2bf(A[1].x * inv) | ((unsigned int)f2bf(A[1].y * inv) << 16);
        o.z = (unsigned int)f2bf(A[2].x * inv) | ((unsigned int)f2bf(A[2].y * inv) << 16);
        o.w = (unsigned int)f2bf(A[3].x * inv) | ((unsigned int)f2bf(A[3].y * inv) << 16);
        *(uint4*)(A2w + (size_t)node * 64 + sub * 4) = o;
    }
}

// ---------------- MFMA GEMMs (no LDS; B^T in registers) ----------------

// h = relu(A1 @ Bt1^T + b1): bf16 into A2 h-half AND fp8 into H8
__global__ __launch_bounds__(256) void k_gemm1(const unsigned short* __restrict__ A1,
                                               const unsigned short* __restrict__ Bt1,
                                               const float* __restrict__ b1,
                                               unsigned short* __restrict__ A2s,
                                               unsigned char* __restrict__ H8b) {
    int wave = (blockIdx.x * 256 + threadIdx.x) >> 6;
    int lane = threadIdx.x & 63;
    int m = lane & 15, quad = lane >> 4;
    if (wave >= NSTRIPS) return;
    short8 bf[4][2];
#pragma unroll
    for (int t = 0; t < 4; t++)
#pragma unroll
        for (int s = 0; s < 2; s++)
            bf[t][s] = *(const short8*)(Bt1 + (t * 16 + m) * 64 + s * 32 + quad * 8);
    float bias[4];
#pragma unroll
    for (int t = 0; t < 4; t++) bias[t] = b1[t * 16 + m];

    int row0 = wave * 16;
    short8 a0 = *(const short8*)(A1 + (row0 + m) * 64 + quad * 8);
    short8 a1 = *(const short8*)(A1 + (row0 + m) * 64 + 32 + quad * 8);
    float4_ acc[4];
#pragma unroll
    for (int t = 0; t < 4; t++) {
        float4_ c = {0.f, 0.f, 0.f, 0.f};
        c = __builtin_amdgcn_mfma_f32_16x16x32_bf16(a0, bf[t][0], c, 0, 0, 0);
        c = __builtin_amdgcn_mfma_f32_16x16x32_bf16(a1, bf[t][1], c, 0, 0, 0);
        acc[t] = c;
    }
#pragma unroll
    for (int t = 0; t < 4; t++) {
        int col = t * 16 + m;
#pragma unroll
        for (int r = 0; r < 4; r++) {
            int row = row0 + quad * 4 + r;
            float v = fmaxf(acc[t][r] + bias[t], 0.f);
            A2s[row * 128 + 64 + col] = f2bf(v);
            H8b[row * 64 + col] =
                (unsigned char)(__builtin_amdgcn_cvt_pk_fp8_f32(v, 0.f, 0, false) & 0xFF);
        }
    }
}

__global__ __launch_bounds__(256) void k_gemm2(const unsigned short* __restrict__ Bt2,
                                               const float* __restrict__ bias2,
                                               unsigned short* A2s,
                                               float* logits) {
    int wave = (blockIdx.x * 256 + threadIdx.x) >> 6;
    int lane = threadIdx.x & 63;
    int m = lane & 15, quad = lane >> 4;
    if (wave >= NSTRIPS) return;
    short8 bf[5][4];
#pragma unroll
    for (int t = 0; t < 5; t++)
#pragma unroll
        for (int s = 0; s < 4; s++)
            bf[t][s] = *(const short8*)(Bt2 + (t * 16 + m) * 128 + s * 32 + quad * 8);
    float bias[5];
#pragma unroll
    for (int t = 0; t < 5; t++) bias[t] = bias2[t * 16 + m];

    int row0 = wave * 16;
    short8 a[4];
#pragma unroll
    for (int s = 0; s < 4; s++)
        a[s] = *(const short8*)(A2s + (row0 + m) * 128 + s * 32 + quad * 8);
    float4_ acc[5];
#pragma unroll
    for (int t = 0; t < 5; t++) {
        float4_ c = {0.f, 0.f, 0.f, 0.f};
#pragma unroll
        for (int s = 0; s < 4; s++)
            c = __builtin_amdgcn_mfma_f32_16x16x32_bf16(a[s], bf[t][s], c, 0, 0, 0);
        acc[t] = c;
    }
    float* embp = (float*)A2s;
#pragma unroll
    for (int t = 0; t < 4; t++) {
#pragma unroll
        for (int r = 0; r < 4; r++) {
            int row = row0 + quad * 4 + r;
            embp[row * 64 + t * 16 + m] = acc[t][r] + bias[t];
        }
    }
#pragma unroll
    for (int r = 0; r < 4; r++) {
        int row = row0 + quad * 4 + r;
        logits[row * 16 + m] = acc[4][r] + bias[4];
    }
}

// ---------------- launch ----------------

extern "C" void kernel_launch(void* const* d_in, const int* in_sizes, int n_in,
                              void* d_out, int out_size, void* d_ws, size_t ws_size,
                              hipStream_t stream) {
    const float* x = (const float*)d_in[0];
    const int* edge = (const int*)d_in[1];
    const int* srcIdx = edge;
    const int* dstIdx = edge + N_EDGES;
    const float* W1l = (const float*)d_in[2];
    const float* b1  = (const float*)d_in[3];
    const float* W1r = (const float*)d_in[4];
    const float* W2l = (const float*)d_in[5];
    const float* b2  = (const float*)d_in[6];
    const float* W2r = (const float*)d_in[7];
    const float* Wc  = (const float*)d_in[8];
    const float* bc  = (const float*)d_in[9];

    float* logits = (float*)d_out;
    unsigned short* A2s = (unsigned short*)((float*)d_out + (size_t)N_NODES * N_CLASSES);
    unsigned int* A2u = (unsigned int*)A2s;

    char* w = (char*)d_ws;
    auto carve = [&](size_t bytes) {
        char* p = w;
        w += (bytes + 255) & ~(size_t)255;
        return p;
    };
    int* rowptr          = (int*)carve((N_NODES + 1) * sizeof(int));
    int* srcs            = (int*)carve((size_t)(N_EDGES + 32) * sizeof(int));
    unsigned int* A1u    = (unsigned int*)carve((size_t)N_NODES * 32 * sizeof(unsigned int));
    unsigned short* X8s  = (unsigned short*)carve((size_t)N_NODES * 32);   // fp8 x, 32B rows
    unsigned char* H8b   = (unsigned char*)carve((size_t)N_NODES * 64);    // fp8 h, 64B rows
    int* bucketCnt       = (int*)carve(NBUCK * sizeof(int));
    int* bucketBase      = (int*)carve((NBUCK + 1) * sizeof(int));
    int* bucketFill      = (int*)carve(NBUCK * sizeof(int));
    unsigned short* Bt1  = (unsigned short*)carve(64 * 64 * sizeof(unsigned short));
    unsigned short* Bt2  = (unsigned short*)carve(80 * 128 * sizeof(unsigned short));
    float* bias2         = (float*)carve(80 * sizeof(float));

    unsigned int* pedges = (unsigned int*)A1u;   // consumed by k_bucket before k_castx writes A1
    unsigned short* A1s = (unsigned short*)A1u;
    unsigned int* X8u = (unsigned int*)X8s;
    unsigned int* H8u = (unsigned int*)H8b;

    k_prep<<<1, 256, 0, stream>>>(W1l, W1r, W2l, W2r, Wc, b2, bc, Bt1, Bt2, bias2);

    hipMemsetAsync(bucketCnt, 0, NBUCK * sizeof(int), stream);
    k_phist<<<PHBLOCKS, 1024, 0, stream>>>(dstIdx, bucketCnt);
    k_scanb<<<1, 1024, 0, stream>>>(bucketCnt, bucketBase, bucketFill, srcs, N_EDGES);
    k_part<<<PTBLOCKS, 1024, 0, stream>>>(srcIdx, dstIdx, bucketFill, pedges);
    k_bucket<<<NBUCK, 1024, 0, stream>>>(pedges, bucketBase, rowptr, srcs,
                                         N_NODES, N_EDGES);

    k_castx<<<(N_NODES * 16 + 255) / 256, 256, 0, stream>>>(x, A1u, X8s);
    k_agg1<<<(N_NODES * 64 + 255) / 256, 256, 0, stream>>>(X8u, rowptr, srcs, A1u, N_NODES);
    k_gemm1<<<(NSTRIPS + 3) / 4, 256, 0, stream>>>(A1s, Bt1, b1, A2s, H8b);
    k_agg2<<<(N_NODES * 64 + 255) / 256, 256, 0, stream>>>(H8u, rowptr, srcs, A2u, N_NODES);
    k_gemm2<<<(NSTRIPS + 3) / 4, 256, 0, stream>>>(Bt2, bias2, A2s, logits);
}